// Round 11
// baseline (1473.760 us; speedup 1.0000x reference)
//
#include <hip/hip_runtime.h>
#include <hip/hip_bf16.h>
#include <stdint.h>

typedef __bf16 bf16x8 __attribute__((ext_vector_type(8)));
typedef __bf16 bf16x4 __attribute__((ext_vector_type(4)));
typedef __bf16 bf16x2 __attribute__((ext_vector_type(2)));
typedef float  f32x4  __attribute__((ext_vector_type(4)));

template <int V> struct ic { static constexpr int value = V; };

__device__ __forceinline__ void gload_lds16(const void* g, void* l) {
  __builtin_amdgcn_global_load_lds(
      (const __attribute__((address_space(1))) void*)g,
      (__attribute__((address_space(3))) void*)l, 16, 0, 0);
}

// ---------------- RMSNorm: fp32 row (H=2048) -> bf16 row ----------------
__global__ __launch_bounds__(256) void rmsnorm_kernel(
    const float* __restrict__ x, const float* __restrict__ w,
    __bf16* __restrict__ out) {
  constexpr int H = 2048;
  const int row = blockIdx.x;
  const int t = threadIdx.x;
  const float4* xr = (const float4*)(x + (size_t)row * H);
  float4 a = xr[t * 2 + 0];
  float4 b = xr[t * 2 + 1];
  float ss = a.x*a.x + a.y*a.y + a.z*a.z + a.w*a.w
           + b.x*b.x + b.y*b.y + b.z*b.z + b.w*b.w;
#pragma unroll
  for (int o = 32; o > 0; o >>= 1) ss += __shfl_xor(ss, o);
  __shared__ float red[4];
  if ((t & 63) == 0) red[t >> 6] = ss;
  __syncthreads();
  float tot = red[0] + red[1] + red[2] + red[3];
  float r = rsqrtf(tot * (1.0f / H) + 1e-6f);
  const float4* wr4 = (const float4*)w;
  float4 wa = wr4[t * 2 + 0];
  float4 wb = wr4[t * 2 + 1];
  bf16x8 ov;
  ov[0] = (__bf16)(a.x * wa.x * r);
  ov[1] = (__bf16)(a.y * wa.y * r);
  ov[2] = (__bf16)(a.z * wa.z * r);
  ov[3] = (__bf16)(a.w * wa.w * r);
  ov[4] = (__bf16)(b.x * wb.x * r);
  ov[5] = (__bf16)(b.y * wb.y * r);
  ov[6] = (__bf16)(b.z * wb.z * r);
  ov[7] = (__bf16)(b.w * wb.w * r);
  *(bf16x8*)(out + (size_t)row * H + (size_t)t * 8) = ov;
}

// ---------------- AWQ dequant -> transposed bf16 weight (N x K) ----------------
template <int GU>
__global__ __launch_bounds__(256) void dequant_t_kernel(
    const int* __restrict__ qw, const int* __restrict__ qz,
    const float* __restrict__ sc, __bf16* __restrict__ wt,
    int K, int Cp, int Nfull) {
  const int t = threadIdx.x;
  const int k0 = blockIdx.x * 128 + (t & 63) * 2;
  const int c0 = blockIdx.y * 64 + (t >> 6) * 16;
  const int g = k0 >> 7;
  const uint32_t* qw0 = (const uint32_t*)qw + (size_t)k0 * Cp + c0;
  const uint32_t* qw1 = qw0 + Cp;
  const uint32_t* qzr = (const uint32_t*)qz + (size_t)g * Cp + c0;
  const float* scr = sc + (size_t)g * Nfull + (size_t)c0 * 8;

  uint32_t u0[16], u1[16], z[16];
#pragma unroll
  for (int j = 0; j < 4; j++) {
    *(int4*)(&u0[j*4]) = *(const int4*)(qw0 + j*4);
    *(int4*)(&u1[j*4]) = *(const int4*)(qw1 + j*4);
    *(int4*)(&z[j*4])  = *(const int4*)(qzr + j*4);
  }

#pragma unroll
  for (int i = 0; i < 16; i++) {
#pragma unroll
    for (int s = 0; s < 8; s++) {
      const int sh = ((s >> 1) * 4) + ((s & 1) ? 16 : 0);
      const float zf = (float)((z[i] >> sh) & 15u);
      const float scv = scr[i * 8 + s];
      const float w0 = ((float)((u0[i] >> sh) & 15u) - zf) * scv;
      const float w1 = ((float)((u1[i] >> sh) & 15u) - zf) * scv;
      const int n = (c0 + i) * 8 + s;
      int row;
      if (GU) row = (n < 8192) ? ((n >> 4) * 32 + (n & 15))
                               : (((n - 8192) >> 4) * 32 + 16 + (n & 15));
      else    row = n;
      bf16x2 pv = {(__bf16)w0, (__bf16)w1};
      *(bf16x2*)(wt + (size_t)row * K + k0) = pv;
    }
  }
}

// ---------------- r7-exact deep-pipelined 256xBN bf16 GEMM -------------------
template <int BN, int EPI, int KC>
__global__ __launch_bounds__(512, 2) void gemm8p_kernel(
    const __bf16* __restrict__ A, const __bf16* __restrict__ Bt,
    void* __restrict__ Cv, const float* __restrict__ addend,
    int M, int N) {
  constexpr int NT = KC / 64;
  constexpr int BQ = BN / 64;
  constexpr int NSTRIP = BN / 4;
  constexpr int NI = NSTRIP / 16;

  __shared__ alignas(16) __bf16 As[8 * 4096];
  __shared__ alignas(16) __bf16 Bs[2 * BQ * 4096];

  const int t = threadIdx.x;
  const int w = t >> 6, l = t & 63;
  const int lm = l & 15, kb = l >> 4;
  const int l7 = lm & 7;
  const int wm = w >> 2, wn = w & 3;

  const size_t stat = (size_t)(t >> 3) * KC + (size_t)(((t & 7) ^ ((t >> 3) & 7)) << 3);

  const int nwg = gridDim.x;
  const int bid = blockIdx.x;
  const int swz = (bid & 7) * (nwg >> 3) + (bid >> 3);
  const int nbm = M >> 8;
  const int per_g = nbm * 8;
  const int grp = swz / per_g, v = swz % per_g;
  const int bm0 = (v % nbm) * 256;
  const int bn0 = (grp * 8 + v / nbm) * BN;

  const __bf16* Ab = A + (size_t)bm0 * KC;
  const __bf16* Bb = Bt + (size_t)bn0 * KC;

  const uint32_t gsw0 = (uint32_t)((kb ^ l7) << 4);
  const uint32_t gsw1 = (uint32_t)(((4 + kb) ^ l7) << 4);
  const uint32_t arow = (uint32_t)(wm * 16384 + lm * 128);
  const uint32_t aoff0 = arow + gsw0, aoff1 = arow + gsw1;
  const uint32_t brow = (BN == 256)
      ? (uint32_t)(wn * 8192 + lm * 128)
      : (uint32_t)((wn >> 1) * 8192 + (wn & 1) * 4096 + lm * 128);
  const uint32_t boff0 = brow + gsw0, boff1 = brow + gsw1;
  const char* AsC = (const char*)As;
  const char* BsC = (const char*)Bs;

  f32x4 acc[8][NI] = {};
  bf16x8 af[2][2][2];
  bf16x8 bfr[2][NI][2];

  auto ldAf = [&](int dD, int mi, bf16x8* dst) {
    const uint32_t imA = (uint32_t)((dD * 4 + (mi >> 2)) * 8192 + (mi & 3) * 2048);
    dst[0] = *(const bf16x8*)(AsC + aoff0 + imA);
    dst[1] = *(const bf16x8*)(AsC + aoff1 + imA);
  };
  auto ldBf = [&](int dD) {
#pragma unroll
    for (int ni = 0; ni < NI; ++ni) {
      const uint32_t imB = (uint32_t)(dD * BQ * 8192 + ni * 2048);
      bfr[dD][ni][0] = *(const bf16x8*)(BsC + boff0 + imB);
      bfr[dD][ni][1] = *(const bf16x8*)(BsC + boff1 + imB);
    }
  };
  auto mfma4 = [&](int q, bf16x8 afq[2][2], int dD) {
    __builtin_amdgcn_s_setprio(1);
#pragma unroll
    for (int kk = 0; kk < 2; ++kk)
#pragma unroll
      for (int ni = 0; ni < NI; ++ni)
#pragma unroll
        for (int m2 = 0; m2 < 2; ++m2)
          acc[q * 2 + m2][ni] = __builtin_amdgcn_mfma_f32_16x16x32_bf16(
              afq[m2][kk], bfr[dD][ni][kk], acc[q * 2 + m2][ni], 0, 0, 0);
    __builtin_amdgcn_s_setprio(0);
  };

#pragma unroll
  for (int qa = 0; qa < 4; ++qa)
    gload_lds16(Ab + stat + (size_t)(qa * 64) * KC, As + qa * 4096 + t * 8);
#pragma unroll
  for (int qb = 0; qb < BQ; ++qb)
    gload_lds16(Bb + stat + (size_t)(qb * 64) * KC, Bs + qb * 4096 + t * 8);
#pragma unroll
  for (int qb = 0; qb < BQ; ++qb)
    gload_lds16(Bb + stat + (size_t)(qb * 64) * KC + 64, Bs + (BQ + qb) * 4096 + t * 8);
  gload_lds16(Ab + stat + 64, As + 4 * 4096 + t * 8);
  gload_lds16(Ab + stat + (size_t)128 * KC + 64, As + 6 * 4096 + t * 8);
  if (BN == 256) asm volatile("s_waitcnt vmcnt(6)" ::: "memory");
  else           asm volatile("s_waitcnt vmcnt(4)" ::: "memory");
  __builtin_amdgcn_s_barrier();

  ldAf(0, 0, af[0][0]); ldAf(0, 1, af[0][1]);
  ldBf(0);
  asm volatile("" ::: "memory");

  const __bf16* pA0 = Ab + stat + 128;
  const __bf16* pA1 = Ab + stat + (size_t)64 * KC + 64;
  const __bf16* pA2 = Ab + stat + (size_t)128 * KC + 128;
  const __bf16* pA3 = Ab + stat + (size_t)192 * KC + 64;
  const __bf16* pB0 = Bb + stat + 128;
  const __bf16* pB1 = Bb + stat + (size_t)64 * KC + 128;
  const __bf16* pB2 = Bb + stat + (size_t)128 * KC + 128;
  const __bf16* pB3 = Bb + stat + (size_t)192 * KC + 128;

  auto tile = [&](auto Dc, auto Sc) {
    constexpr int D = decltype(Dc)::value;
    constexpr int STG = decltype(Sc)::value;
    // ph0
    ldAf(D, 2, af[1][0]); ldAf(D, 3, af[1][1]);
    asm volatile("" ::: "memory");
    if (STG >= 1) {
      gload_lds16(pA1, As + ((D ^ 1) * 4 + 1) * 4096 + t * 8);
      gload_lds16(pA3, As + ((D ^ 1) * 4 + 3) * 4096 + t * 8);
    }
    __builtin_amdgcn_s_barrier();
    mfma4(0, af[0], D);
    __builtin_amdgcn_s_barrier();
    // ph1
    ldAf(D, 4, af[0][0]); ldAf(D, 5, af[0][1]);
    asm volatile("" ::: "memory");
    if (STG == 2) {
      gload_lds16(pB0, Bs + (D * BQ + 0) * 4096 + t * 8);
      gload_lds16(pB1, Bs + (D * BQ + 1) * 4096 + t * 8);
    }
    __builtin_amdgcn_s_barrier();
    mfma4(1, af[1], D);
    __builtin_amdgcn_s_barrier();
    // ph2
    ldAf(D, 6, af[1][0]); ldAf(D, 7, af[1][1]);
    asm volatile("" ::: "memory");
    if (STG == 2) {
      if (BN == 256) {
        gload_lds16(pB2, Bs + (D * BQ + 2) * 4096 + t * 8);
        gload_lds16(pB3, Bs + (D * BQ + 3) * 4096 + t * 8);
      } else {
        gload_lds16(pA0, As + (D * 4 + 0) * 4096 + t * 8);
        gload_lds16(pA2, As + (D * 4 + 2) * 4096 + t * 8);
      }
    }
    __builtin_amdgcn_s_barrier();
    mfma4(2, af[0], D);
    __builtin_amdgcn_s_barrier();
    // ph3 (publish)
    asm volatile("s_waitcnt lgkmcnt(0)" ::: "memory");
    __builtin_amdgcn_sched_barrier(0);
    if (STG == 2)      asm volatile("s_waitcnt vmcnt(4)" ::: "memory");
    else if (STG == 1) asm volatile("s_waitcnt vmcnt(0)" ::: "memory");
    __builtin_amdgcn_s_barrier();
    if (STG >= 1) {
      ldAf(D ^ 1, 0, af[0][0]); ldAf(D ^ 1, 1, af[0][1]);
      ldBf(D ^ 1);
    }
    if (STG == 2 && BN == 256) {
      gload_lds16(pA0, As + (D * 4 + 0) * 4096 + t * 8);
      gload_lds16(pA2, As + (D * 4 + 2) * 4096 + t * 8);
    }
    __builtin_amdgcn_sched_barrier(0);
    mfma4(3, af[1], D);
    __builtin_amdgcn_s_barrier();
    if (STG == 2) {
      pA0 += 64; pA1 += 64; pA2 += 64; pA3 += 64;
      pB0 += 64; pB1 += 64;
      if (BN == 256) { pB2 += 64; pB3 += 64; }
    }
  };

#pragma unroll 1
  for (int it = 0; it < NT / 2 - 1; ++it) {
    tile(ic<0>{}, ic<2>{});
    tile(ic<1>{}, ic<2>{});
  }
  tile(ic<0>{}, ic<1>{});
  tile(ic<1>{}, ic<0>{});

  const int crow0 = bm0 + wm * 128;
#pragma unroll
  for (int mi = 0; mi < 8; ++mi) {
    if (EPI == 2) {
#pragma unroll
      for (int p = 0; p < NI / 2; ++p) {
        const int ni = p * 2;
        const int col = ((bn0 + wn * 64 + ni * 16) >> 5) * 16 + lm;
#pragma unroll
        for (int r = 0; r < 4; ++r) {
          const int row = crow0 + mi * 16 + kb * 4 + r;
          const float gv = acc[mi][ni][r], uv = acc[mi][ni + 1][r];
          const float av = uv * (gv / (1.0f + __expf(-gv)));
          ((__bf16*)Cv)[(size_t)row * 8192 + col] = (__bf16)av;
        }
      }
    } else {
#pragma unroll
      for (int ni = 0; ni < NI; ++ni) {
        const int col = bn0 + wn * NSTRIP + ni * 16 + lm;
#pragma unroll
        for (int r = 0; r < 4; ++r) {
          const int row = crow0 + mi * 16 + kb * 4 + r;
          const size_t idx = (size_t)row * N + col;
          if (EPI == 0) ((__bf16*)Cv)[idx] = (__bf16)acc[mi][ni][r];
          else          ((float*)Cv)[idx] = addend[idx] + acc[mi][ni][r];
        }
      }
    }
  }
}

// -------- gu GEMM: BN=256, EPI=silu, B staged INT4 -> dequant in-kernel -------
// B supply per tile: 8 KB int4 (vs 32 KB bf16). Same LDS layout/read path as
// gemm8p. Per thread: task = (c, 4-k slab): 4 dword loads (issued tile t-1
// ph2, 3-phase cover), unpack + 8 ds_write_b64 at tile t ph1/ph2 (s-rotated,
// <=4-way conflicts; scales pre-staggered at load so all reg indexing static).
// Steady vmcnt(4): [Aeven(t+1)x2, Aodd(t+1)x2 | keep bq(t+3)x4]. Tails peeled:
// STG 2 (t<=28) / 3 (t=29: unpack, no B-issue/sc, vmcnt0) / 1 (t=30) / 0.
__global__ __launch_bounds__(512, 2) void gemm_gu_kernel(
    const __bf16* __restrict__ A, const int* __restrict__ qw,
    const int* __restrict__ qz, const float* __restrict__ sc,
    __bf16* __restrict__ act, int M) {
  constexpr int KC = 2048, NT = 32, BQ = 4, NI = 4, Cp = 2048;

  __shared__ alignas(16) __bf16 As[8 * 4096];
  __shared__ alignas(16) __bf16 Bs[2 * BQ * 4096];

  const int t = threadIdx.x;
  const int w = t >> 6, l = t & 63;
  const int lm = l & 15, kb = l >> 4;
  const int l7 = lm & 7;
  const int wm = w >> 2, wn = w & 3;

  const size_t stat = (size_t)(t >> 3) * KC + (size_t)(((t & 7) ^ ((t >> 3) & 7)) << 3);

  const int nwg = gridDim.x;
  const int bid = blockIdx.x;
  const int swz = (bid & 7) * (nwg >> 3) + (bid >> 3);
  const int nbm = M >> 8;
  const int per_g = nbm * 8;
  const int grp = swz / per_g, v = swz % per_g;
  const int bm0 = (v % nbm) * 256;
  const int bn0 = (grp * 8 + v / nbm) * 256;

  const __bf16* Ab = A + (size_t)bm0 * KC;

  // ---- B int4 task geometry ----
  const int cl = t & 31;
  const int kslab = t >> 5;               // 0..15, k0 = kslab*4
  const int k0 = kslab * 4;
  const int clg = (cl < 16) ? cl : (cl - 16);
  const int rl0 = ((clg >> 1) << 5) + ((clg & 1) << 3) + ((cl < 16) ? 0 : 16);
  const int c = (cl < 16) ? ((bn0 >> 4) + cl) : (1024 + (bn0 >> 4) + cl - 16);
  const uint32_t G = (uint32_t)(kslab >> 1);
  const uint32_t wOff = (uint32_t)(((rl0 >> 6) << 13) + ((rl0 & 63) << 7) + ((kslab & 1) << 3));
  const uint32_t rot = (uint32_t)(t & 7);
  const uint32_t* qcol = (const uint32_t*)qw + c;
  const uint32_t* qzc  = (const uint32_t*)qz + c;
  const float*    scc  = sc + (size_t)c * 8;

  const uint32_t gsw0 = (uint32_t)((kb ^ l7) << 4);
  const uint32_t gsw1 = (uint32_t)(((4 + kb) ^ l7) << 4);
  const uint32_t arow = (uint32_t)(wm * 16384 + lm * 128);
  const uint32_t aoff0 = arow + gsw0, aoff1 = arow + gsw1;
  const uint32_t boff0 = (uint32_t)(wn * 8192 + lm * 128) + gsw0;
  const uint32_t boff1 = (uint32_t)(wn * 8192 + lm * 128) + gsw1;
  const char* AsC = (const char*)As;
  const char* BsC = (const char*)Bs;
  char* BsW = (char*)Bs;

  f32x4 acc[8][NI] = {};
  bf16x8 af[2][2][2];
  bf16x8 bfr[NI][2];          // single-buffered (loaded each tile at ph0)
  uint32_t bq[4];
  float scf[8];
  uint32_t qzv = 0;

  auto ldAf = [&](int dD, int mi, bf16x8* dst) {
    const uint32_t imA = (uint32_t)((dD * 4 + (mi >> 2)) * 8192 + (mi & 3) * 2048);
    dst[0] = *(const bf16x8*)(AsC + aoff0 + imA);
    dst[1] = *(const bf16x8*)(AsC + aoff1 + imA);
  };
  auto ldBf = [&](int dD) {
#pragma unroll
    for (int ni = 0; ni < NI; ++ni) {
      const uint32_t imB = (uint32_t)(dD * 32768 + ni * 2048);
      bfr[ni][0] = *(const bf16x8*)(BsC + boff0 + imB);
      bfr[ni][1] = *(const bf16x8*)(BsC + boff1 + imB);
    }
  };
  auto mfma4 = [&](int q, bf16x8 afq[2][2]) {
    __builtin_amdgcn_s_setprio(1);
#pragma unroll
    for (int kk = 0; kk < 2; ++kk)
#pragma unroll
      for (int ni = 0; ni < NI; ++ni)
#pragma unroll
        for (int m2 = 0; m2 < 2; ++m2)
          acc[q * 2 + m2][ni] = __builtin_amdgcn_mfma_f32_16x16x32_bf16(
              afq[m2][kk], bfr[ni][kk], acc[q * 2 + m2][ni], 0, 0, 0);
    __builtin_amdgcn_s_setprio(0);
  };
  auto unpackWrite = [&](int Dd, int sp0, int sp1) {
#pragma unroll
    for (int sp = sp0; sp < sp1; ++sp) {
      const uint32_t s = (uint32_t)((sp + rot) & 7);
      const uint32_t sh = ((s >> 1) << 2) | ((s & 1) << 4);
      const float zf = (float)((qzv >> sh) & 15u);
      const float scv = scf[sp];
      bf16x4 vv;
#pragma unroll
      for (int i = 0; i < 4; ++i)
        vv[i] = (__bf16)(((float)((bq[i] >> sh) & 15u) - zf) * scv);
      *(bf16x4*)(BsW + Dd * 32768 + wOff + (s << 7) + ((G ^ s) << 4)) = vv;
    }
  };

  // ---- prologue ----
#pragma unroll
  for (int qa = 0; qa < 4; ++qa)
    gload_lds16(Ab + stat + (size_t)(qa * 64) * KC, As + qa * 4096 + t * 8);
  gload_lds16(Ab + stat + 64, As + 4 * 4096 + t * 8);
  gload_lds16(Ab + stat + (size_t)128 * KC + 64, As + 6 * 4096 + t * 8);
  // sc/qz group 0
  qzv = qzc[0];
#pragma unroll
  for (int sp = 0; sp < 8; ++sp) scf[sp] = scc[(sp + rot) & 7];
  // B0 -> Bs[0]
#pragma unroll
  for (int i = 0; i < 4; ++i) bq[i] = qcol[(size_t)(k0 + i) * Cp];
  unpackWrite(0, 0, 8);
  // B1 -> Bs[1]
#pragma unroll
  for (int i = 0; i < 4; ++i) bq[i] = qcol[(size_t)(64 + k0 + i) * Cp];
  unpackWrite(1, 0, 8);
  // B2 int4 (for tile0 unpack) + sc/qz group1
#pragma unroll
  for (int i = 0; i < 4; ++i) bq[i] = qcol[(size_t)(128 + k0 + i) * Cp];
  qzv = qzc[2048];
#pragma unroll
  for (int sp = 0; sp < 8; ++sp) scf[sp] = scc[16384 + ((sp + rot) & 7)];
  asm volatile("s_waitcnt lgkmcnt(0)" ::: "memory");
  __builtin_amdgcn_s_barrier();
  ldAf(0, 0, af[0][0]); ldAf(0, 1, af[0][1]);
  asm volatile("" ::: "memory");

  const __bf16* pA0 = Ab + stat + 128;
  const __bf16* pA1 = Ab + stat + (size_t)64 * KC + 64;
  const __bf16* pA2 = Ab + stat + (size_t)128 * KC + 128;
  const __bf16* pA3 = Ab + stat + (size_t)192 * KC + 64;
  const uint32_t* pBq = qcol + (size_t)(k0 + 192) * Cp;
  const float* scd = scc + 16384;      // currently-loaded group (g1)
  const uint32_t* qzd = qzc + 2048;

  auto tile = [&](auto Dc, auto Sc) {
    constexpr int D = decltype(Dc)::value;
    constexpr int STG = decltype(Sc)::value;  // 2 steady, 3 t=NT-3, 1 t=NT-2, 0 last
    // ph0
    ldBf(D);
    ldAf(D, 2, af[1][0]); ldAf(D, 3, af[1][1]);
    asm volatile("" ::: "memory");
    if (STG >= 1) {
      gload_lds16(pA1, As + ((D ^ 1) * 4 + 1) * 4096 + t * 8);
      gload_lds16(pA3, As + ((D ^ 1) * 4 + 3) * 4096 + t * 8);
    }
    __builtin_amdgcn_s_barrier();
    mfma4(0, af[0]);
    __builtin_amdgcn_s_barrier();
    // ph1
    ldAf(D, 4, af[0][0]); ldAf(D, 5, af[0][1]);
    asm volatile("" ::: "memory");
    if (STG >= 2) unpackWrite(D, 0, 4);    // B(t+2) rows 0-3 -> Bs[D]
    __builtin_amdgcn_s_barrier();
    mfma4(1, af[1]);
    __builtin_amdgcn_s_barrier();
    // ph2
    ldAf(D, 6, af[1][0]); ldAf(D, 7, af[1][1]);
    asm volatile("" ::: "memory");
    if (STG >= 2) unpackWrite(D, 4, 8);    // B(t+2) rows 4-7
    if (STG == 2) {
#pragma unroll
      for (int i = 0; i < 4; ++i) bq[i] = pBq[(size_t)i * Cp];  // B(t+3) int4
    }
    __builtin_amdgcn_s_barrier();
    mfma4(2, af[0]);
    __builtin_amdgcn_s_barrier();
    // ph3 (publish)
    asm volatile("s_waitcnt lgkmcnt(0)" ::: "memory");
    __builtin_amdgcn_sched_barrier(0);
    if (STG == 2)      asm volatile("s_waitcnt vmcnt(4)" ::: "memory");
    else if (STG == 3 || STG == 1) asm volatile("s_waitcnt vmcnt(0)" ::: "memory");
    __builtin_amdgcn_s_barrier();
    if (STG == 2) {                        // sc/qz for B(t+3)'s group
      if (D == 1) { scd += 16384; qzd += 2048; }
      qzv = qzd[0];
#pragma unroll
      for (int sp = 0; sp < 8; ++sp) scf[sp] = scd[(sp + rot) & 7];
    }
    if (STG >= 1) { ldAf(D ^ 1, 0, af[0][0]); ldAf(D ^ 1, 1, af[0][1]); }
    if (STG >= 2) {
      gload_lds16(pA0, As + (D * 4 + 0) * 4096 + t * 8);
      gload_lds16(pA2, As + (D * 4 + 2) * 4096 + t * 8);
    }
    __builtin_amdgcn_sched_barrier(0);
    mfma4(3, af[1]);
    __builtin_amdgcn_s_barrier();
    if (STG >= 2) { pA0 += 64; pA1 += 64; pA2 += 64; pA3 += 64; }
    if (STG == 2) pBq += (size_t)64 * Cp;
  };

#pragma unroll 1
  for (int it = 0; it < 14; ++it) {   // t = 0..27
    tile(ic<0>{}, ic<2>{});
    tile(ic<1>{}, ic<2>{});
  }
  tile(ic<0>{}, ic<2>{});   // t = 28 (issues B(31), loads its sc)
  tile(ic<1>{}, ic<3>{});   // t = 29 (unpacks B(31); vmcnt0)
  tile(ic<0>{}, ic<1>{});   // t = 30
  tile(ic<1>{}, ic<0>{});   // t = 31

  // ---- epilogue: silu(gate)*up, gate/up 16-col interleave ----
  const int crow0 = bm0 + wm * 128;
#pragma unroll
  for (int mi = 0; mi < 8; ++mi) {
#pragma unroll
    for (int p = 0; p < 2; ++p) {
      const int ni = p * 2;
      const int col = ((bn0 + wn * 64 + ni * 16) >> 5) * 16 + lm;
#pragma unroll
      for (int r = 0; r < 4; ++r) {
        const int row = crow0 + mi * 16 + kb * 4 + r;
        const float gv = acc[mi][ni][r], uv = acc[mi][ni + 1][r];
        const float av = uv * (gv / (1.0f + __expf(-gv)));
        act[(size_t)row * 8192 + col] = (__bf16)av;
      }
    }
  }
}

extern "C" void kernel_launch(void* const* d_in, const int* in_sizes, int n_in,
                              void* d_out, int out_size, void* d_ws, size_t ws_size,
                              hipStream_t stream) {
  const float* x      = (const float*)d_in[0];
  const float* ln1    = (const float*)d_in[1];
  const float* ln2    = (const float*)d_in[2];
  const int*   qkv_qw = (const int*)d_in[3];
  const int*   qkv_qz = (const int*)d_in[4];
  const float* qkv_sc = (const float*)d_in[5];
  const int*   o_qw   = (const int*)d_in[6];
  const int*   o_qz   = (const int*)d_in[7];
  const float* o_sc   = (const float*)d_in[8];
  const int*   gu_qw  = (const int*)d_in[9];
  const int*   gu_qz  = (const int*)d_in[10];
  const float* gu_sc  = (const float*)d_in[11];
  const int*   dn_qw  = (const int*)d_in[12];
  const int*   dn_qz  = (const int*)d_in[13];
  const float* dn_sc  = (const float*)d_in[14];

  constexpr int M = 4096;

  char* ws = (char*)d_ws;
  __bf16* h   = (__bf16*)(ws + 0);                 // 16 MiB
  __bf16* q   = (__bf16*)(ws + 16777216ULL);       // 16 MiB
  float*  x2  = (float*)(ws + 33554432ULL);        // 32 MiB
  __bf16* W   = (__bf16*)(ws + 67108864ULL);       // weight^T (q/o/dn only)
  __bf16* act = (__bf16*)(ws + 134217728ULL);      // [4096][8192]
  __bf16* Wdn = (__bf16*)(ws + 0);                 // reuses h/q (dead by then)

  // 1. h1 = rmsnorm(x, ln1)
  rmsnorm_kernel<<<dim3(M), dim3(256), 0, stream>>>(x, ln1, h);
  // 2. Wq^T (only first 2048 cols of qkv used)
  dequant_t_kernel<0><<<dim3(16, 4), dim3(256), 0, stream>>>(qkv_qw, qkv_qz, qkv_sc, W, 2048, 768, 6144);
  // 3. q = h1 @ Wq
  gemm8p_kernel<128, 0, 2048><<<dim3(256), dim3(512), 0, stream>>>(h, W, (void*)q, nullptr, M, 2048);
  // 4. Wo^T
  dequant_t_kernel<0><<<dim3(16, 4), dim3(256), 0, stream>>>(o_qw, o_qz, o_sc, W, 2048, 256, 2048);
  // 5. x2 = x + q @ Wo
  gemm8p_kernel<128, 1, 2048><<<dim3(256), dim3(512), 0, stream>>>(q, W, (void*)x2, x, M, 2048);
  // 6. h2 = rmsnorm(x2, ln2)
  rmsnorm_kernel<<<dim3(M), dim3(256), 0, stream>>>(x2, ln2, h);
  // 7. act = silu(gate)*up — int4-fused gu GEMM (no dequant pass)
  gemm_gu_kernel<<<dim3(1024), dim3(512), 0, stream>>>(h, gu_qw, gu_qz, gu_sc, act, M);
  // 8. Wdn^T [2048][8192]
  dequant_t_kernel<0><<<dim3(64, 4), dim3(256), 0, stream>>>(dn_qw, dn_qz, dn_sc, Wdn, 8192, 256, 2048);
  // 9. out = x2 + act @ Wdn
  gemm8p_kernel<128, 1, 8192><<<dim3(256), dim3(512), 0, stream>>>(act, Wdn, d_out, x2, M, 2048);
}

// Round 12
// 516.091 us; speedup vs baseline: 2.8556x; 2.8556x over previous
//
#include <hip/hip_runtime.h>
#include <hip/hip_bf16.h>
#include <stdint.h>

typedef __bf16 bf16x8 __attribute__((ext_vector_type(8)));
typedef __bf16 bf16x2 __attribute__((ext_vector_type(2)));
typedef float  f32x4  __attribute__((ext_vector_type(4)));

template <int V> struct ic { static constexpr int value = V; };

__device__ __forceinline__ void gload_lds16(const void* g, void* l) {
  __builtin_amdgcn_global_load_lds(
      (const __attribute__((address_space(1))) void*)g,
      (__attribute__((address_space(3))) void*)l, 16, 0, 0);
}

// ---------------- RMSNorm: fp32 row (H=2048) -> bf16 row ----------------
__global__ __launch_bounds__(256) void rmsnorm_kernel(
    const float* __restrict__ x, const float* __restrict__ w,
    __bf16* __restrict__ out) {
  constexpr int H = 2048;
  const int row = blockIdx.x;
  const int t = threadIdx.x;
  const float4* xr = (const float4*)(x + (size_t)row * H);
  float4 a = xr[t * 2 + 0];
  float4 b = xr[t * 2 + 1];
  float ss = a.x*a.x + a.y*a.y + a.z*a.z + a.w*a.w
           + b.x*b.x + b.y*b.y + b.z*b.z + b.w*b.w;
#pragma unroll
  for (int o = 32; o > 0; o >>= 1) ss += __shfl_xor(ss, o);
  __shared__ float red[4];
  if ((t & 63) == 0) red[t >> 6] = ss;
  __syncthreads();
  float tot = red[0] + red[1] + red[2] + red[3];
  float r = rsqrtf(tot * (1.0f / H) + 1e-6f);
  const float4* wr4 = (const float4*)w;
  float4 wa = wr4[t * 2 + 0];
  float4 wb = wr4[t * 2 + 1];
  bf16x8 ov;
  ov[0] = (__bf16)(a.x * wa.x * r);
  ov[1] = (__bf16)(a.y * wa.y * r);
  ov[2] = (__bf16)(a.z * wa.z * r);
  ov[3] = (__bf16)(a.w * wa.w * r);
  ov[4] = (__bf16)(b.x * wb.x * r);
  ov[5] = (__bf16)(b.y * wb.y * r);
  ov[6] = (__bf16)(b.z * wb.z * r);
  ov[7] = (__bf16)(b.w * wb.w * r);
  *(bf16x8*)(out + (size_t)row * H + (size_t)t * 8) = ov;
}

// ---------------- AWQ dequant -> transposed bf16 weight (N x K) ----------------
template <int GU>
__global__ __launch_bounds__(256) void dequant_t_kernel(
    const int* __restrict__ qw, const int* __restrict__ qz,
    const float* __restrict__ sc, __bf16* __restrict__ wt,
    int K, int Cp, int Nfull) {
  const int t = threadIdx.x;
  const int k0 = blockIdx.x * 128 + (t & 63) * 2;
  const int c0 = blockIdx.y * 64 + (t >> 6) * 16;
  const int g = k0 >> 7;
  const uint32_t* qw0 = (const uint32_t*)qw + (size_t)k0 * Cp + c0;
  const uint32_t* qw1 = qw0 + Cp;
  const uint32_t* qzr = (const uint32_t*)qz + (size_t)g * Cp + c0;
  const float* scr = sc + (size_t)g * Nfull + (size_t)c0 * 8;

  uint32_t u0[16], u1[16], z[16];
#pragma unroll
  for (int j = 0; j < 4; j++) {
    *(int4*)(&u0[j*4]) = *(const int4*)(qw0 + j*4);
    *(int4*)(&u1[j*4]) = *(const int4*)(qw1 + j*4);
    *(int4*)(&z[j*4])  = *(const int4*)(qzr + j*4);
  }

#pragma unroll
  for (int i = 0; i < 16; i++) {
#pragma unroll
    for (int s = 0; s < 8; s++) {
      const int sh = ((s >> 1) * 4) + ((s & 1) ? 16 : 0);
      const float zf = (float)((z[i] >> sh) & 15u);
      const float scv = scr[i * 8 + s];
      const float w0 = ((float)((u0[i] >> sh) & 15u) - zf) * scv;
      const float w1 = ((float)((u1[i] >> sh) & 15u) - zf) * scv;
      const int n = (c0 + i) * 8 + s;
      int row;
      if (GU) row = (n < 8192) ? ((n >> 4) * 32 + (n & 15))
                               : (((n - 8192) >> 4) * 32 + 16 + (n & 15));
      else    row = n;
      bf16x2 pv = {(__bf16)w0, (__bf16)w1};
      *(bf16x2*)(wt + (size_t)row * K + k0) = pv;
    }
  }
}

// ---------------- r7-exact deep-pipelined 256xBN bf16 GEMM (gu only) ---------
template <int BN, int EPI, int KC>
__global__ __launch_bounds__(512, 2) void gemm8p_kernel(
    const __bf16* __restrict__ A, const __bf16* __restrict__ Bt,
    void* __restrict__ Cv, const float* __restrict__ addend,
    int M, int N) {
  constexpr int NT = KC / 64;
  constexpr int BQ = BN / 64;
  constexpr int NSTRIP = BN / 4;
  constexpr int NI = NSTRIP / 16;

  __shared__ alignas(16) __bf16 As[8 * 4096];
  __shared__ alignas(16) __bf16 Bs[2 * BQ * 4096];

  const int t = threadIdx.x;
  const int w = t >> 6, l = t & 63;
  const int lm = l & 15, kb = l >> 4;
  const int l7 = lm & 7;
  const int wm = w >> 2, wn = w & 3;

  const size_t stat = (size_t)(t >> 3) * KC + (size_t)(((t & 7) ^ ((t >> 3) & 7)) << 3);

  const int nwg = gridDim.x;
  const int bid = blockIdx.x;
  const int swz = (bid & 7) * (nwg >> 3) + (bid >> 3);
  const int nbm = M >> 8;
  const int per_g = nbm * 8;
  const int grp = swz / per_g, v = swz % per_g;
  const int bm0 = (v % nbm) * 256;
  const int bn0 = (grp * 8 + v / nbm) * BN;

  const __bf16* Ab = A + (size_t)bm0 * KC;
  const __bf16* Bb = Bt + (size_t)bn0 * KC;

  const uint32_t gsw0 = (uint32_t)((kb ^ l7) << 4);
  const uint32_t gsw1 = (uint32_t)(((4 + kb) ^ l7) << 4);
  const uint32_t arow = (uint32_t)(wm * 16384 + lm * 128);
  const uint32_t aoff0 = arow + gsw0, aoff1 = arow + gsw1;
  const uint32_t brow = (BN == 256)
      ? (uint32_t)(wn * 8192 + lm * 128)
      : (uint32_t)((wn >> 1) * 8192 + (wn & 1) * 4096 + lm * 128);
  const uint32_t boff0 = brow + gsw0, boff1 = brow + gsw1;
  const char* AsC = (const char*)As;
  const char* BsC = (const char*)Bs;

  f32x4 acc[8][NI] = {};
  bf16x8 af[2][2][2];
  bf16x8 bfr[2][NI][2];

  auto ldAf = [&](int dD, int mi, bf16x8* dst) {
    const uint32_t imA = (uint32_t)((dD * 4 + (mi >> 2)) * 8192 + (mi & 3) * 2048);
    dst[0] = *(const bf16x8*)(AsC + aoff0 + imA);
    dst[1] = *(const bf16x8*)(AsC + aoff1 + imA);
  };
  auto ldBf = [&](int dD) {
#pragma unroll
    for (int ni = 0; ni < NI; ++ni) {
      const uint32_t imB = (uint32_t)(dD * BQ * 8192 + ni * 2048);
      bfr[dD][ni][0] = *(const bf16x8*)(BsC + boff0 + imB);
      bfr[dD][ni][1] = *(const bf16x8*)(BsC + boff1 + imB);
    }
  };
  auto mfma4 = [&](int q, bf16x8 afq[2][2], int dD) {
    __builtin_amdgcn_s_setprio(1);
#pragma unroll
    for (int kk = 0; kk < 2; ++kk)
#pragma unroll
      for (int ni = 0; ni < NI; ++ni)
#pragma unroll
        for (int m2 = 0; m2 < 2; ++m2)
          acc[q * 2 + m2][ni] = __builtin_amdgcn_mfma_f32_16x16x32_bf16(
              afq[m2][kk], bfr[dD][ni][kk], acc[q * 2 + m2][ni], 0, 0, 0);
    __builtin_amdgcn_s_setprio(0);
  };

#pragma unroll
  for (int qa = 0; qa < 4; ++qa)
    gload_lds16(Ab + stat + (size_t)(qa * 64) * KC, As + qa * 4096 + t * 8);
#pragma unroll
  for (int qb = 0; qb < BQ; ++qb)
    gload_lds16(Bb + stat + (size_t)(qb * 64) * KC, Bs + qb * 4096 + t * 8);
#pragma unroll
  for (int qb = 0; qb < BQ; ++qb)
    gload_lds16(Bb + stat + (size_t)(qb * 64) * KC + 64, Bs + (BQ + qb) * 4096 + t * 8);
  gload_lds16(Ab + stat + 64, As + 4 * 4096 + t * 8);
  gload_lds16(Ab + stat + (size_t)128 * KC + 64, As + 6 * 4096 + t * 8);
  if (BN == 256) asm volatile("s_waitcnt vmcnt(6)" ::: "memory");
  else           asm volatile("s_waitcnt vmcnt(4)" ::: "memory");
  __builtin_amdgcn_s_barrier();

  ldAf(0, 0, af[0][0]); ldAf(0, 1, af[0][1]);
  ldBf(0);
  asm volatile("" ::: "memory");

  const __bf16* pA0 = Ab + stat + 128;
  const __bf16* pA1 = Ab + stat + (size_t)64 * KC + 64;
  const __bf16* pA2 = Ab + stat + (size_t)128 * KC + 128;
  const __bf16* pA3 = Ab + stat + (size_t)192 * KC + 64;
  const __bf16* pB0 = Bb + stat + 128;
  const __bf16* pB1 = Bb + stat + (size_t)64 * KC + 128;
  const __bf16* pB2 = Bb + stat + (size_t)128 * KC + 128;
  const __bf16* pB3 = Bb + stat + (size_t)192 * KC + 128;

  auto tile = [&](auto Dc, auto Sc) {
    constexpr int D = decltype(Dc)::value;
    constexpr int STG = decltype(Sc)::value;
    // ph0
    ldAf(D, 2, af[1][0]); ldAf(D, 3, af[1][1]);
    asm volatile("" ::: "memory");
    if (STG >= 1) {
      gload_lds16(pA1, As + ((D ^ 1) * 4 + 1) * 4096 + t * 8);
      gload_lds16(pA3, As + ((D ^ 1) * 4 + 3) * 4096 + t * 8);
    }
    __builtin_amdgcn_s_barrier();
    mfma4(0, af[0], D);
    __builtin_amdgcn_s_barrier();
    // ph1
    ldAf(D, 4, af[0][0]); ldAf(D, 5, af[0][1]);
    asm volatile("" ::: "memory");
    if (STG == 2) {
      gload_lds16(pB0, Bs + (D * BQ + 0) * 4096 + t * 8);
      gload_lds16(pB1, Bs + (D * BQ + 1) * 4096 + t * 8);
    }
    __builtin_amdgcn_s_barrier();
    mfma4(1, af[1], D);
    __builtin_amdgcn_s_barrier();
    // ph2
    ldAf(D, 6, af[1][0]); ldAf(D, 7, af[1][1]);
    asm volatile("" ::: "memory");
    if (STG == 2) {
      if (BN == 256) {
        gload_lds16(pB2, Bs + (D * BQ + 2) * 4096 + t * 8);
        gload_lds16(pB3, Bs + (D * BQ + 3) * 4096 + t * 8);
      } else {
        gload_lds16(pA0, As + (D * 4 + 0) * 4096 + t * 8);
        gload_lds16(pA2, As + (D * 4 + 2) * 4096 + t * 8);
      }
    }
    __builtin_amdgcn_s_barrier();
    mfma4(2, af[0], D);
    __builtin_amdgcn_s_barrier();
    // ph3 (publish)
    asm volatile("s_waitcnt lgkmcnt(0)" ::: "memory");
    __builtin_amdgcn_sched_barrier(0);
    if (STG == 2)      asm volatile("s_waitcnt vmcnt(4)" ::: "memory");
    else if (STG == 1) asm volatile("s_waitcnt vmcnt(0)" ::: "memory");
    __builtin_amdgcn_s_barrier();
    if (STG >= 1) {
      ldAf(D ^ 1, 0, af[0][0]); ldAf(D ^ 1, 1, af[0][1]);
      ldBf(D ^ 1);
    }
    if (STG == 2 && BN == 256) {
      gload_lds16(pA0, As + (D * 4 + 0) * 4096 + t * 8);
      gload_lds16(pA2, As + (D * 4 + 2) * 4096 + t * 8);
    }
    __builtin_amdgcn_sched_barrier(0);
    mfma4(3, af[1], D);
    __builtin_amdgcn_s_barrier();
    if (STG == 2) {
      pA0 += 64; pA1 += 64; pA2 += 64; pA3 += 64;
      pB0 += 64; pB1 += 64;
      if (BN == 256) { pB2 += 64; pB3 += 64; }
    }
  };

#pragma unroll 1
  for (int it = 0; it < NT / 2 - 1; ++it) {
    tile(ic<0>{}, ic<2>{});
    tile(ic<1>{}, ic<2>{});
  }
  tile(ic<0>{}, ic<1>{});
  tile(ic<1>{}, ic<0>{});

  const int crow0 = bm0 + wm * 128;
#pragma unroll
  for (int mi = 0; mi < 8; ++mi) {
    if (EPI == 2) {
#pragma unroll
      for (int p = 0; p < NI / 2; ++p) {
        const int ni = p * 2;
        const int col = ((bn0 + wn * 64 + ni * 16) >> 5) * 16 + lm;
#pragma unroll
        for (int r = 0; r < 4; ++r) {
          const int row = crow0 + mi * 16 + kb * 4 + r;
          const float gv = acc[mi][ni][r], uv = acc[mi][ni + 1][r];
          const float av = uv * (gv / (1.0f + __expf(-gv)));
          ((__bf16*)Cv)[(size_t)row * 8192 + col] = (__bf16)av;
        }
      }
    } else {
#pragma unroll
      for (int ni = 0; ni < NI; ++ni) {
        const int col = bn0 + wn * NSTRIP + ni * 16 + lm;
#pragma unroll
        for (int r = 0; r < 4; ++r) {
          const int row = crow0 + mi * 16 + kb * 4 + r;
          const size_t idx = (size_t)row * N + col;
          if (EPI == 0) ((__bf16*)Cv)[idx] = (__bf16)acc[mi][ni][r];
          else          ((float*)Cv)[idx] = addend[idx] + acc[mi][ni][r];
        }
      }
    }
  }
}

// ---------- 128x128 GEMM, 64 KB LDS -> 2 WGs/CU (q, o, dn) -------------------
// r7 skeleton re-ledgered for 2 A/B quarters. Per wave (2m x 4n): rows
// {wm*32+(mi&1)*16 | q=mi>>1}, cols wn*32 (NI=2). Quarter q0 dead after
// ph1-barrier -> stage A(t+2)q0 at ph2; q1 dead at tile end -> stage
// A(t+1)q1 at ph0; B(t+2) at ph1. Steady vmcnt(3) (leftovers carry:
// [B(t+1)^2,q0(t+1)] + [q1(t+1),B(t+2)^2,q0(t+2)] -> drain thru q1(t+1)).
// Prologue 7 loads, vmcnt(3). Tails: STG=1 stages q1 only + vmcnt(0); STG=0 none.
template <int EPI, int KC>
__global__ __launch_bounds__(512, 4) void gemm128_kernel(
    const __bf16* __restrict__ A, const __bf16* __restrict__ Bt,
    void* __restrict__ Cv, const float* __restrict__ addend,
    int M, int N) {
  constexpr int NT = KC / 64;

  __shared__ alignas(16) __bf16 As[4 * 4096];   // [d*2+q][64 rows x 64 k swz]
  __shared__ alignas(16) __bf16 Bs[4 * 4096];

  const int t = threadIdx.x;
  const int w = t >> 6, l = t & 63;
  const int lm = l & 15, kb = l >> 4;
  const int l7 = lm & 7;
  const int wm = w >> 2, wn = w & 3;   // wm 0..1 (row halves), wn 0..3

  const size_t stat = (size_t)(t >> 3) * KC + (size_t)(((t & 7) ^ ((t >> 3) & 7)) << 3);

  const int nwg = gridDim.x;
  const int bid = blockIdx.x;
  const int swz = (bid & 7) * (nwg >> 3) + (bid >> 3);
  const int nbm = M >> 7;
  const int per_g = nbm * 8;
  const int grp = swz / per_g, v = swz % per_g;
  const int bm0 = (v % nbm) * 128;
  const int bn0 = (grp * 8 + v / nbm) * 128;

  const __bf16* Ab = A + (size_t)bm0 * KC;
  const __bf16* Bb = Bt + (size_t)bn0 * KC;

  const uint32_t gsw0 = (uint32_t)((kb ^ l7) << 4);
  const uint32_t gsw1 = (uint32_t)(((4 + kb) ^ l7) << 4);
  const uint32_t aoff0 = (uint32_t)((wm * 32 + lm) * 128) + gsw0;
  const uint32_t aoff1 = (uint32_t)((wm * 32 + lm) * 128) + gsw1;
  const uint32_t bbase = (uint32_t)(((wn & 1) * 32 + lm) * 128 + (wn >> 1) * 8192);
  const uint32_t boff0 = bbase + gsw0, boff1 = bbase + gsw1;
  const char* AsC = (const char*)As;
  const char* BsC = (const char*)Bs;

  f32x4 acc[4][2] = {};
  bf16x8 af[2][2];          // [mi parity][kk]
  bf16x8 bfr[2][2][2];      // [tile parity][ni][kk]

  auto ldAf = [&](int dD, int mi) {   // dD, mi compile-time at call
    const uint32_t imA = (uint32_t)((dD * 2 + (mi >> 1)) * 8192 + (mi & 1) * 2048);
    af[mi & 1][0] = *(const bf16x8*)(AsC + aoff0 + imA);
    af[mi & 1][1] = *(const bf16x8*)(AsC + aoff1 + imA);
  };
  auto ldBf = [&](int dD) {
#pragma unroll
    for (int ni = 0; ni < 2; ++ni) {
      const uint32_t imB = (uint32_t)(dD * 16384 + ni * 2048);
      bfr[dD][ni][0] = *(const bf16x8*)(BsC + boff0 + imB);
      bfr[dD][ni][1] = *(const bf16x8*)(BsC + boff1 + imB);
    }
  };
  auto mfma1 = [&](int mi, int dD) {  // mi, dD compile-time at call
    __builtin_amdgcn_s_setprio(1);
#pragma unroll
    for (int kk = 0; kk < 2; ++kk)
#pragma unroll
      for (int ni = 0; ni < 2; ++ni)
        acc[mi][ni] = __builtin_amdgcn_mfma_f32_16x16x32_bf16(
            af[mi & 1][kk], bfr[dD][ni][kk], acc[mi][ni], 0, 0, 0);
    __builtin_amdgcn_s_setprio(0);
  };

  // ---- prologue: A(0)q0,q1; B(0)q0,q1; B(1)q0,q1; A(1)q0 -> vmcnt(3) ----
  gload_lds16(Ab + stat,                        As + 0 * 4096 + t * 8);
  gload_lds16(Ab + stat + (size_t)64 * KC,      As + 1 * 4096 + t * 8);
  gload_lds16(Bb + stat,                        Bs + 0 * 4096 + t * 8);
  gload_lds16(Bb + stat + (size_t)64 * KC,      Bs + 1 * 4096 + t * 8);
  gload_lds16(Bb + stat + 64,                   Bs + 2 * 4096 + t * 8);
  gload_lds16(Bb + stat + (size_t)64 * KC + 64, Bs + 3 * 4096 + t * 8);
  gload_lds16(Ab + stat + 64,                   As + 2 * 4096 + t * 8);
  asm volatile("s_waitcnt vmcnt(3)" ::: "memory");
  __builtin_amdgcn_s_barrier();

  ldAf(0, 0);
  ldBf(0);
  asm volatile("" ::: "memory");

  // stream pointers at first steady-tile use (kt=0)
  const __bf16* pAq1 = Ab + stat + (size_t)64 * KC + 64;   // A(t+1) q1
  const __bf16* pAq0 = Ab + stat + 128;                    // A(t+2) q0
  const __bf16* pBq0 = Bb + stat + 128;                    // B(t+2) q0
  const __bf16* pBq1 = Bb + stat + (size_t)64 * KC + 128;  // B(t+2) q1

  auto tile = [&](auto Dc, auto Sc) {
    constexpr int D = decltype(Dc)::value;
    constexpr int STG = decltype(Sc)::value;
    // ph0
    ldAf(D, 1);
    asm volatile("" ::: "memory");
    if (STG >= 1)
      gload_lds16(pAq1, As + ((D ^ 1) * 2 + 1) * 4096 + t * 8);
    __builtin_amdgcn_s_barrier();
    mfma1(0, D);
    __builtin_amdgcn_s_barrier();
    // ph1
    ldAf(D, 2);
    asm volatile("" ::: "memory");
    if (STG == 2) {
      gload_lds16(pBq0, Bs + (D * 2 + 0) * 4096 + t * 8);
      gload_lds16(pBq1, Bs + (D * 2 + 1) * 4096 + t * 8);
    }
    __builtin_amdgcn_s_barrier();
    mfma1(1, D);
    __builtin_amdgcn_s_barrier();
    // ph2 (q0 of this tile dead since ph1-barrier -> safe to overwrite)
    ldAf(D, 3);
    asm volatile("" ::: "memory");
    if (STG == 2)
      gload_lds16(pAq0, As + (D * 2 + 0) * 4096 + t * 8);
    __builtin_amdgcn_s_barrier();
    mfma1(2, D);
    __builtin_amdgcn_s_barrier();
    // ph3 (publish tile t+1)
    asm volatile("s_waitcnt lgkmcnt(0)" ::: "memory");
    __builtin_amdgcn_sched_barrier(0);
    if (STG == 2)      asm volatile("s_waitcnt vmcnt(3)" ::: "memory");
    else if (STG == 1) asm volatile("s_waitcnt vmcnt(0)" ::: "memory");
    __builtin_amdgcn_s_barrier();
    if (STG >= 1) {
      ldAf(D ^ 1, 0);
      ldBf(D ^ 1);
    }
    __builtin_amdgcn_sched_barrier(0);
    mfma1(3, D);
    __builtin_amdgcn_s_barrier();
    if (STG == 2) { pAq0 += 64; pAq1 += 64; pBq0 += 64; pBq1 += 64; }
  };

#pragma unroll 1
  for (int it = 0; it < NT / 2 - 1; ++it) {
    tile(ic<0>{}, ic<2>{});
    tile(ic<1>{}, ic<2>{});
  }
  tile(ic<0>{}, ic<1>{});   // kt = NT-2
  tile(ic<1>{}, ic<0>{});   // kt = NT-1

  // ---- epilogue ----
#pragma unroll
  for (int mi = 0; mi < 4; ++mi) {
#pragma unroll
    for (int ni = 0; ni < 2; ++ni) {
      const int col = bn0 + wn * 32 + ni * 16 + lm;
#pragma unroll
      for (int r = 0; r < 4; ++r) {
        const int row = bm0 + (mi >> 1) * 64 + wm * 32 + (mi & 1) * 16 + kb * 4 + r;
        const size_t idx = (size_t)row * N + col;
        if (EPI == 0) ((__bf16*)Cv)[idx] = (__bf16)acc[mi][ni][r];
        else          ((float*)Cv)[idx] = addend[idx] + acc[mi][ni][r];
      }
    }
  }
}

extern "C" void kernel_launch(void* const* d_in, const int* in_sizes, int n_in,
                              void* d_out, int out_size, void* d_ws, size_t ws_size,
                              hipStream_t stream) {
  const float* x      = (const float*)d_in[0];
  const float* ln1    = (const float*)d_in[1];
  const float* ln2    = (const float*)d_in[2];
  const int*   qkv_qw = (const int*)d_in[3];
  const int*   qkv_qz = (const int*)d_in[4];
  const float* qkv_sc = (const float*)d_in[5];
  const int*   o_qw   = (const int*)d_in[6];
  const int*   o_qz   = (const int*)d_in[7];
  const float* o_sc   = (const float*)d_in[8];
  const int*   gu_qw  = (const int*)d_in[9];
  const int*   gu_qz  = (const int*)d_in[10];
  const float* gu_sc  = (const float*)d_in[11];
  const int*   dn_qw  = (const int*)d_in[12];
  const int*   dn_qz  = (const int*)d_in[13];
  const float* dn_sc  = (const float*)d_in[14];

  constexpr int M = 4096;

  char* ws = (char*)d_ws;
  __bf16* h   = (__bf16*)(ws + 0);                 // 16 MiB
  __bf16* q   = (__bf16*)(ws + 16777216ULL);       // 16 MiB
  float*  x2  = (float*)(ws + 33554432ULL);        // 32 MiB
  __bf16* W   = (__bf16*)(ws + 67108864ULL);       // 64 MiB weight^T (reused)
  __bf16* act = (__bf16*)(ws + 134217728ULL);      // 64 MiB [4096][8192]
  __bf16* Wdn = (__bf16*)(ws + 0);                 // 32 MiB (h,q dead by then)

  // 1. h1 = rmsnorm(x, ln1)
  rmsnorm_kernel<<<dim3(M), dim3(256), 0, stream>>>(x, ln1, h);
  // 2. Wq^T (only first 2048 cols of qkv used)
  dequant_t_kernel<0><<<dim3(16, 4), dim3(256), 0, stream>>>(qkv_qw, qkv_qz, qkv_sc, W, 2048, 768, 6144);
  // 3. q = h1 @ Wq
  gemm128_kernel<0, 2048><<<dim3(512), dim3(512), 0, stream>>>(h, W, (void*)q, nullptr, M, 2048);
  // 4. Wo^T
  dequant_t_kernel<0><<<dim3(16, 4), dim3(256), 0, stream>>>(o_qw, o_qz, o_sc, W, 2048, 256, 2048);
  // 5. x2 = x + q @ Wo
  gemm128_kernel<1, 2048><<<dim3(512), dim3(512), 0, stream>>>(q, W, (void*)x2, x, M, 2048);
  // 6. h2 = rmsnorm(x2, ln2)
  rmsnorm_kernel<<<dim3(M), dim3(256), 0, stream>>>(x2, ln2, h);
  // 7. Wgu^T [16384][2048], gate/up 16-col interleaved
  dequant_t_kernel<1><<<dim3(16, 32), dim3(256), 0, stream>>>(gu_qw, gu_qz, gu_sc, W, 2048, 2048, 16384);
  // 8. act = silu(gate)*up fused into GEMM epilogue
  gemm8p_kernel<256, 2, 2048><<<dim3(1024), dim3(512), 0, stream>>>(h, W, (void*)act, nullptr, M, 16384);
  // 9. Wdn^T [2048][8192]
  dequant_t_kernel<0><<<dim3(64, 4), dim3(256), 0, stream>>>(dn_qw, dn_qz, dn_sc, Wdn, 8192, 256, 2048);
  // 10. out = x2 + act @ Wdn
  gemm128_kernel<1, 8192><<<dim3(512), dim3(512), 0, stream>>>(act, Wdn, d_out, x2, M, 2048);
}